// Round 16
// baseline (327.848 us; speedup 1.0000x reference)
//
#include <hip/hip_runtime.h>
#include <cstddef>

// Problem constants
constexpr int Bn  = 512;
constexpr int Dd  = 960;
constexpr int RL  = 16;
constexpr int RD  = 32;
constexpr int LPp = 16;
constexpr int LHh = 384;
constexpr int DP  = 358;
constexpr int DH  = 154;
constexpr int CH  = 128;   // A-chunk rows staged in LDS

typedef float f32x4 __attribute__((ext_vector_type(4)));

struct EncIn {
    const float* X;     // (B, L, 960)
    const int*   mask;  // (B, L) contiguous prefix
    const float* A;     // (L, 16)
    const float* Bc;    // (960, 32)
    int L;
};

// =====================================================================
// K0: zero the work-queue counter (ws is poisoned 0xAA by harness).
// =====================================================================
__global__ void zero_kernel(int* __restrict__ q)
{
    if (threadIdx.x == 0) *q = 0;
}

// =====================================================================
// K1: persistent stream + U ONLY (r9's proven body, tails removed).
// 512-thread blocks, grid 512 -> 2 blocks/CU, 16 waves/CU.
// Stream: 2 row-groups x 240 lanes x f32x4, A in LDS chunks (off the
//   vmcnt queue), UNCONDITIONAL clamped one-row lookahead (branchless ->
//   compiler keeps 2 loads in flight always).
// U: thread t=(p,r) computes one U entry, #pragma unroll 2 (16 Bc loads
//   in flight), writes U to ws (2 KB/item, coalesced).
// z/MLP1/MLP2 moved OUT to batched GEMMs (they were ~15us/item of
//   L2-latency-bound serial matvec on the per-CU critical path; as
//   GEMMs they get x64 weight reuse and cost ~30us total).
// =====================================================================
__global__ __launch_bounds__(512)
void stream_kernel(EncIn H, EncIn P, int* __restrict__ qcnt,
                   float* __restrict__ Uws)
{
    const int t = threadIdx.x;
    __shared__ float Vs[RL][Dd];     // 61440 B
    __shared__ float As[CH * RL];    //  8192 B
    __shared__ int   s_item, s_len;

    const int  grp = t >> 8;         // row-group 0..1
    const int  w   = t & 255;
    const bool act = (w < 240);      // 240 lanes x 4 cols = 960
    const int  col = 4 * w;

    for (;;) {
        __syncthreads();             // protect LDS reuse across items
        if (t == 0) { s_item = atomicAdd(qcnt, 1); s_len = 0; }
        __syncthreads();
        const int item = s_item;
        if (item >= 2 * Bn) return;
        const bool isH = (item < Bn);
        const EncIn E = isH ? H : P;
        const int b = isH ? item : item - Bn;

        // ---- len = popcount of contiguous-prefix mask row ----
        int loc = 0;
        for (int i = t; i < E.L; i += 512) loc += E.mask[(size_t)b * E.L + i];
        if (loc) atomicAdd(&s_len, loc);
        __syncthreads();
        const int len = s_len;

        // ---- stream phase: V = A^T Xm, group g owns rows l%2==g ----
        float v[RL][4];
        #pragma unroll
        for (int p = 0; p < RL; ++p)
            { v[p][0] = 0.f; v[p][1] = 0.f; v[p][2] = 0.f; v[p][3] = 0.f; }

        const float* Xb = E.X + (size_t)b * E.L * Dd;

        for (int c0 = 0; c0 < len; c0 += CH) {
            __syncthreads();         // prior chunk's As reads done
            {   // stage A chunk (128 rows x 16), rows >= len zeroed
                const int row = c0 + (t >> 2);
                f32x4 av = {0.f, 0.f, 0.f, 0.f};
                if (row < len)
                    av = *(const f32x4*)(E.A + (size_t)row * RL + (t & 3) * 4);
                *(f32x4*)&As[(t >> 2) * RL + (t & 3) * 4] = av;
            }
            __syncthreads();

            if (act) {
                const int lim = min(len, c0 + CH);
                int l = c0 + grp;
                if (l < lim) {
                    const float* rp    = Xb + (size_t)l * Dd + col;
                    const float* rpmax = Xb + (size_t)(E.L - 1) * Dd + col;
                    f32x4 x = __builtin_nontemporal_load((const f32x4*)rp);
                    for (; l < lim; l += 2) {
                        // unconditional clamped lookahead (branchless):
                        const float* rp2 = rp + 2 * (size_t)Dd;
                        rp2 = (rp2 > rpmax) ? rpmax : rp2;
                        f32x4 xn = __builtin_nontemporal_load((const f32x4*)rp2);
                        rp = rp2;
                        float a[RL];
                        const int lr = l - c0;
                        *(f32x4*)&a[0]  = *(const f32x4*)&As[lr * RL + 0];
                        *(f32x4*)&a[4]  = *(const f32x4*)&As[lr * RL + 4];
                        *(f32x4*)&a[8]  = *(const f32x4*)&As[lr * RL + 8];
                        *(f32x4*)&a[12] = *(const f32x4*)&As[lr * RL + 12];
                        #pragma unroll
                        for (int p = 0; p < RL; ++p) {
                            v[p][0] = fmaf(a[p], x[0], v[p][0]);
                            v[p][1] = fmaf(a[p], x[1], v[p][1]);
                            v[p][2] = fmaf(a[p], x[2], v[p][2]);
                            v[p][3] = fmaf(a[p], x[3], v[p][3]);
                        }
                        x = xn;
                    }
                }
            }
        }

        // ---- combine the two row-groups into Vs ----
        __syncthreads();
        if (grp == 0 && act) {
            #pragma unroll
            for (int p = 0; p < RL; ++p)
                *(f32x4*)&Vs[p][col] = *(f32x4*)&v[p][0];
        }
        __syncthreads();
        if (grp == 1 && act) {
            #pragma unroll
            for (int p = 0; p < RL; ++p) {
                f32x4 cur = *(const f32x4*)&Vs[p][col];
                cur += *(f32x4*)&v[p][0];
                *(f32x4*)&Vs[p][col] = cur;
            }
        }
        __syncthreads();

        // ---- U phase: thread t = (p,r) computes one U entry -> ws ----
        {
            const int p = t >> 5, r = t & 31;
            float u0 = 0.f, u1 = 0.f;
            #pragma unroll 2
            for (int dd = 0; dd < Dd; dd += 8) {
                f32x4 va = *(const f32x4*)&Vs[p][dd];
                f32x4 vb = *(const f32x4*)&Vs[p][dd + 4];
                #pragma unroll
                for (int q = 0; q < 4; ++q) {
                    u0 = fmaf(va[q], E.Bc[(size_t)(dd + q) * RD + r],     u0);
                    u1 = fmaf(vb[q], E.Bc[(size_t)(dd + 4 + q) * RD + r], u1);
                }
            }
            Uws[(size_t)item * 512 + t] = u0 + u1;   // t == p*32 + r
        }
        // loop: top-of-loop barrier protects Vs/As reuse
    }
}

// =====================================================================
// K2/K3/K4 gemm: C = A(512,K) @ W(K,N) [+ bias], P and H in one grid.
//   MODE 0: h = relu((C+bias) * g/sqrt(1+eps) + beta) -> out pitch N
//   MODE 1: C + bias -> d_out[m*(DP+DH) + ooff + c]   (concat store)
//   MODE 2: C -> out pitch N (no bias; the z = U @ Hc stage)
// =====================================================================
template <int MODE>
__global__ __launch_bounds__(256)
void gemm_kernel(const float* __restrict__ AaP, const float* __restrict__ WP,
                 const float* __restrict__ biasP, const float* __restrict__ gPv,
                 const float* __restrict__ betaPv, float* __restrict__ outP,
                 const float* __restrict__ AaH, const float* __restrict__ WH,
                 const float* __restrict__ biasH, const float* __restrict__ gHv,
                 const float* __restrict__ betaHv, float* __restrict__ outH,
                 int nbP, int KP, int NP, int KH, int NH)
{
    const float *Aa, *W, *bias, *g, *beta; float* out;
    int K, N, n0, ooff;
    if ((int)blockIdx.y < nbP) {
        Aa = AaP; W = WP; bias = biasP; g = gPv; beta = betaPv; out = outP;
        K = KP; N = NP; n0 = blockIdx.y * 64; ooff = 0;
    } else {
        Aa = AaH; W = WH; bias = biasH; g = gHv; beta = betaHv; out = outH;
        K = KH; N = NH; n0 = (blockIdx.y - nbP) * 64; ooff = DP;
    }

    constexpr int TM = 64, TN = 64, KC = 32;
    __shared__ float AsT[KC][TM + 4];
    __shared__ float Ws[KC][TN];
    const int t  = threadIdx.x;
    const int m0 = blockIdx.x * TM;
    const int r0 = (t >> 4) << 2;
    const int c0 = (t & 15) << 2;
    float acc[4][4] = {};

    for (int k0 = 0; k0 < K; k0 += KC) {
        for (int i = t; i < TM * KC; i += 256) {
            int row = i >> 5, kk = i & 31;
            int kg = k0 + kk;
            AsT[kk][row] = (kg < K) ? Aa[(size_t)(m0 + row) * K + kg] : 0.f;
        }
        for (int i = t; i < KC * TN; i += 256) {
            int kk = i >> 6, c = i & 63;
            int kg = k0 + kk, cg = n0 + c;
            Ws[kk][c] = (kg < K && cg < N) ? W[(size_t)kg * N + cg] : 0.f;
        }
        __syncthreads();
        #pragma unroll
        for (int kk = 0; kk < KC; ++kk) {
            float4 av = *(const float4*)&AsT[kk][r0];
            float4 wv = *(const float4*)&Ws[kk][c0];
            const float a[4] = {av.x, av.y, av.z, av.w};
            const float wv4[4] = {wv.x, wv.y, wv.z, wv.w};
            #pragma unroll
            for (int i = 0; i < 4; ++i)
                #pragma unroll
                for (int j = 0; j < 4; ++j)
                    acc[i][j] = fmaf(a[i], wv4[j], acc[i][j]);
        }
        __syncthreads();
    }

    const float bscale = rsqrtf(1.f + 1e-5f);
    #pragma unroll
    for (int j = 0; j < 4; ++j) {
        int c = n0 + c0 + j;
        if (c < N) {
            float bb = 0.f, gg = 0.f, be = 0.f;
            if constexpr (MODE != 2) bb = bias[c];
            if constexpr (MODE == 0) { gg = g[c] * bscale; be = beta[c]; }
            #pragma unroll
            for (int i = 0; i < 4; ++i) {
                int m = m0 + r0 + i;
                float vv = acc[i][j] + bb;
                if constexpr (MODE == 0) {
                    vv = fmaf(vv, gg, be);
                    vv = fmaxf(vv, 0.f);
                    out[(size_t)m * N + c] = vv;
                } else if constexpr (MODE == 1) {
                    out[(size_t)m * (DP + DH) + ooff + c] = vv;
                } else {
                    out[(size_t)m * N + c] = vv;
                }
            }
        }
    }
}

// =====================================================================
extern "C" void kernel_launch(void* const* d_in, const int* in_sizes, int n_in,
                              void* d_out, int out_size, void* d_ws, size_t ws_size,
                              hipStream_t stream)
{
    const float* emb_P  = (const float*)d_in[0];
    const float* emb_H  = (const float*)d_in[1];
    const int*   mask_P = (const int*)  d_in[2];
    const int*   mask_H = (const int*)  d_in[3];
    const float* B_cP   = (const float*)d_in[4];
    const float* A_cP   = (const float*)d_in[5];
    const float* H_cP   = (const float*)d_in[6];
    const float* W1P    = (const float*)d_in[7];
    const float* b1P    = (const float*)d_in[8];
    const float* gP     = (const float*)d_in[9];
    const float* betaP  = (const float*)d_in[10];
    const float* W2P    = (const float*)d_in[11];
    const float* b2P    = (const float*)d_in[12];
    const float* B_cH   = (const float*)d_in[13];
    const float* A_cH   = (const float*)d_in[14];
    const float* H_cH   = (const float*)d_in[15];
    const float* W1H    = (const float*)d_in[16];
    const float* b1H    = (const float*)d_in[17];
    const float* gH     = (const float*)d_in[18];
    const float* betaH  = (const float*)d_in[19];
    const float* W2H    = (const float*)d_in[20];
    const float* b2H    = (const float*)d_in[21];
    float* outp = (float*)d_out;

    // workspace layout: qcnt (1 KB pad) | U (1024x512) | z | h
    int*   qcnt = (int*)d_ws;
    float* U_ws = (float*)d_ws + 256;
    float* z_P  = U_ws + (size_t)2 * Bn * 512;   // 512*358
    float* z_H  = z_P + (size_t)Bn * DP;         // 512*154
    float* h_P  = z_H + (size_t)Bn * DH;
    float* h_H  = h_P + (size_t)Bn * DP;

    EncIn Hin, Pin;
    Hin.X = emb_H; Hin.mask = mask_H; Hin.A = A_cH; Hin.Bc = B_cH; Hin.L = LHh;
    Pin.X = emb_P; Pin.mask = mask_P; Pin.A = A_cP; Pin.Bc = B_cP; Pin.L = LPp;

    // K0: zero queue counter
    zero_kernel<<<dim3(1), dim3(64), 0, stream>>>(qcnt);

    // K1: stream + U (items 0..511 = H, 512..1023 = P; H first = LPT)
    stream_kernel<<<dim3(512), dim3(512), 0, stream>>>(Hin, Pin, qcnt, U_ws);

    const float* U_H = U_ws;
    const float* U_P = U_ws + (size_t)Bn * 512;

    // K2: z = U @ Hc (no bias)
    gemm_kernel<2><<<dim3(8, 9), dim3(256), 0, stream>>>(
        U_P, H_cP, nullptr, nullptr, nullptr, z_P,
        U_H, H_cH, nullptr, nullptr, nullptr, z_H,
        6, 512, DP, 512, DH);

    // K3: MLP layer 1 + BN + ReLU
    gemm_kernel<0><<<dim3(8, 9), dim3(256), 0, stream>>>(
        z_P, W1P, b1P, gP, betaP, h_P,
        z_H, W1H, b1H, gH, betaH, h_H,
        6, DP, DP, DH, DH);

    // K4: MLP layer 2 + concat store into d_out
    gemm_kernel<1><<<dim3(8, 9), dim3(256), 0, stream>>>(
        h_P, W2P, b2P, nullptr, nullptr, outp,
        h_H, W2H, b2H, nullptr, nullptr, outp,
        6, DP, DP, DH, DH);
}